// Round 5
// baseline (291.992 us; speedup 1.0000x reference)
//
#include <hip/hip_runtime.h>
#include <hip/hip_bf16.h>

typedef __attribute__((ext_vector_type(4))) float f32x4;
typedef __attribute__((ext_vector_type(8))) short bf16x8;

#define MFMA16(a, b, c) __builtin_amdgcn_mfma_f32_16x16x32_bf16(a, b, c, 0, 0, 0)

#define AS1(p) ((const __attribute__((address_space(1))) void*)(p))
#define AS3(p) ((__attribute__((address_space(3))) void*)(p))

// XOR swizzle of 16B slot within a 128B row (8 slots)
#define SWZK(r) ((((r) & 7)) ^ ((((r) >> 3) & 1) << 2))
// XOR swizzle of 16B slot within a 64B row (4 slots)
#define SWZV(r) ((((r) & 3)) ^ ((((r) >> 2) & 1) << 1))

__device__ __forceinline__ unsigned short f2bf(float f) {
  union { float f; unsigned u; } x; x.f = f;
  unsigned r = x.u + 0x7fffu + ((x.u >> 16) & 1u);  // RNE
  return (unsigned short)(r >> 16);
}

// ---------------- f32 -> bf16, vectorized: 8 elems/thread ------------------
__global__ __launch_bounds__(256) void convert_all(
    const float* __restrict__ x, const float* __restrict__ wq,
    const float* __restrict__ wk, const float* __restrict__ wv,
    const float* __restrict__ wo, unsigned short* __restrict__ dst) {
  const int i = blockIdx.x * 256 + threadIdx.x;  // x8 elements
  const long base = (long)i * 8;
  const int NX = 4194304, NW = 1048576;
  const float* src; long off;
  if (base < NX) { src = x; off = base; }
  else {
    long j = base - NX; int ws = (int)(j >> 20); off = j & (NW - 1);
    src = (ws == 0) ? wq : (ws == 1) ? wk : (ws == 2) ? wv : wo;
  }
  float4 a = *(const float4*)(src + off);
  float4 b = *(const float4*)(src + off + 4);
  uint4 o;
  o.x = (unsigned)f2bf(a.x) | ((unsigned)f2bf(a.y) << 16);
  o.y = (unsigned)f2bf(a.z) | ((unsigned)f2bf(a.w) << 16);
  o.z = (unsigned)f2bf(b.x) | ((unsigned)f2bf(b.y) << 16);
  o.w = (unsigned)f2bf(b.z) | ((unsigned)f2bf(b.w) << 16);
  ((uint4*)dst)[i] = o;
}

// ---------------- int32 mask -> u8 ----------------------------------------
__global__ __launch_bounds__(256) void convert_mask(
    const int* __restrict__ m, unsigned char* __restrict__ o) {
  const int i = blockIdx.x * 256 + threadIdx.x;  // x4 elements
  const int4 v = ((const int4*)m)[i];
  uchar4 r;
  r.x = (unsigned char)v.x; r.y = (unsigned char)v.y;
  r.z = (unsigned char)v.z; r.w = (unsigned char)v.w;
  ((uchar4*)o)[i] = r;
}

// ---------------- templated BMxBN NT GEMM mainloop (C = A * W^T), K=1024 ---
// acc layout: acc[i * (BN/32) + j], wave (wr,wc) covers (BM/2, BN/2).
template <int BM, int BN>
__device__ __forceinline__ void gemm_nt(
    const unsigned short* __restrict__ A, const unsigned short* __restrict__ Bw,
    int m0, int n0, unsigned short* Al, unsigned short* Bl, f32x4* acc) {
  const int t = threadIdx.x;
  const int l = t & 63;
  const int w = t >> 6, wr = w >> 1, wc = w & 1;
  const int lc = l & 15, lg = l >> 4;
  constexpr int MI = BM / 32, NJ = BN / 32;
  constexpr int ASZ = BM * 32, BSZ = BN * 32;

  auto stage = [&](int buf, int kt) {
    const int k0 = kt * 32;
#pragma unroll
    for (int c = 0; c < BM / 64; ++c) {
      const int e = (t + c * 256) * 8;
      __builtin_amdgcn_global_load_lds(
          AS1(A + (size_t)(m0 + (e >> 5)) * 1024 + k0 + (e & 31)),
          AS3(Al + buf * ASZ + e), 16, 0, 0);
    }
#pragma unroll
    for (int c = 0; c < BN / 64; ++c) {
      const int e = (t + c * 256) * 8;
      __builtin_amdgcn_global_load_lds(
          AS1(Bw + (size_t)(n0 + (e >> 5)) * 1024 + k0 + (e & 31)),
          AS3(Bl + buf * BSZ + e), 16, 0, 0);
    }
  };

  stage(0, 0);
#pragma unroll 2
  for (int kt = 0; kt < 32; ++kt) {
    __syncthreads();
    if (kt + 1 < 32) stage((kt + 1) & 1, kt + 1);
    const unsigned short* Ab = Al + (kt & 1) * ASZ;
    const unsigned short* Bb = Bl + (kt & 1) * BSZ;
    bf16x8 af[MI], bfr[NJ];
#pragma unroll
    for (int i = 0; i < MI; ++i)
      af[i] = *(const bf16x8*)(Ab + (wr * (BM / 2) + i * 16 + lc) * 32 + lg * 8);
#pragma unroll
    for (int j = 0; j < NJ; ++j)
      bfr[j] = *(const bf16x8*)(Bb + (wc * (BN / 2) + j * 16 + lc) * 32 + lg * 8);
#pragma unroll
    for (int i = 0; i < MI; ++i)
#pragma unroll
      for (int j = 0; j < NJ; ++j)
        acc[i * NJ + j] = MFMA16(af[i], bfr[j], acc[i * NJ + j]);
  }
}

// ---------------- QKV projection: Q,K -> (B,H,S,64); V -> (B,H,64,S) -------
__global__ __launch_bounds__(256) void gemm_qkv(
    const unsigned short* __restrict__ xb,
    const unsigned short* __restrict__ wqb, const unsigned short* __restrict__ wkb,
    const unsigned short* __restrict__ wvb,
    unsigned short* __restrict__ q, unsigned short* __restrict__ k,
    unsigned short* __restrict__ vt) {
  __shared__ unsigned short Al[2 * 4096], Bl[2 * 4096];
  const int z = blockIdx.z;
  const unsigned short* Bw = (z == 0) ? wqb : (z == 1) ? wkb : wvb;
  const int m0 = blockIdx.x * 128, n0 = blockIdx.y * 128;
  f32x4 acc[16] = {};
  gemm_nt<128, 128>(xb, Bw, m0, n0, Al, Bl, acc);

  const int l = threadIdx.x & 63, w = threadIdx.x >> 6;
  const int wr = w >> 1, wc = w & 1, lc = l & 15, lg = l >> 4;

  if (z == 2) {
#pragma unroll
    for (int i = 0; i < 4; ++i)
#pragma unroll
      for (int j = 0; j < 4; ++j) {
        const int m = m0 + wr * 64 + i * 16 + lg * 4;
        const int n = n0 + wc * 64 + j * 16 + lc;
        const int b = m >> 11, s = m & 2047, hh = n >> 6, hd = n & 63;
        ushort4 pk;
        pk.x = f2bf(acc[i * 4 + j][0]); pk.y = f2bf(acc[i * 4 + j][1]);
        pk.z = f2bf(acc[i * 4 + j][2]); pk.w = f2bf(acc[i * 4 + j][3]);
        *(ushort4*)(vt + (size_t)((b << 4) + hh) * 131072 + (size_t)hd * 2048 + s) = pk;
      }
  } else {
    unsigned short* C = (z == 0) ? q : k;
#pragma unroll
    for (int i = 0; i < 4; ++i)
#pragma unroll
      for (int j = 0; j < 4; ++j)
#pragma unroll
        for (int r = 0; r < 4; ++r) {
          const int m = m0 + wr * 64 + i * 16 + lg * 4 + r;
          const int n = n0 + wc * 64 + j * 16 + lc;
          const int b = m >> 11, s = m & 2047, hh = n >> 6, hd = n & 63;
          C[(size_t)((b << 4) + hh) * 131072 + s * 64 + hd] = f2bf(acc[i * 4 + j][r]);
        }
  }
}

// ---------------- output projection: out = ao @ Wo^T + bo, 64x128 tiles ----
__global__ __launch_bounds__(256) void gemm_out(
    const unsigned short* __restrict__ ao, const unsigned short* __restrict__ wob,
    const float* __restrict__ bias, float* __restrict__ out) {
  __shared__ unsigned short Al[2 * 2048], Bl[2 * 4096];
  const int m0 = blockIdx.x * 64, n0 = blockIdx.y * 128;
  f32x4 acc[8] = {};
  gemm_nt<64, 128>(ao, wob, m0, n0, Al, Bl, acc);

  const int l = threadIdx.x & 63, w = threadIdx.x >> 6;
  const int wr = w >> 1, wc = w & 1, lc = l & 15, lg = l >> 4;
#pragma unroll
  for (int i = 0; i < 2; ++i)
#pragma unroll
    for (int j = 0; j < 4; ++j)
#pragma unroll
      for (int r = 0; r < 4; ++r) {
        const int m = m0 + wr * 32 + i * 16 + lg * 4 + r;
        const int n = n0 + wc * 64 + j * 16 + lc;
        out[(size_t)m * 1024 + n] = acc[i * 4 + j][r] + bias[n];
      }
}

// ---------------- flash attention, max-free softmax, KVB=32, 8 blocks/CU ---
// K tile [32 kv][64 d] (128B rows, SWZK); V^T tile [64 d][32 kv] (64B rows,
// SWZV); P per-wave [16 q][32 kv] (64B rows, SWZV).
__global__ __launch_bounds__(256, 8) void attn_fwd(
    const unsigned short* __restrict__ q, const unsigned short* __restrict__ k,
    const unsigned short* __restrict__ vt, const unsigned char* __restrict__ mb8,
    unsigned short* __restrict__ ao) {
  __shared__ unsigned short Kl[2][2048];   // 4KB x2
  __shared__ unsigned short Vl[2][2048];   // 4KB x2
  __shared__ unsigned short Pl[4][512];    // per-wave 16x32, 1KB x4
  // XCD-aware bijective swizzle: 1024 blocks, 8 XCDs, 128 consecutive per XCD
  const int orig = blockIdx.x;
  const int nid = (orig & 7) * 128 + (orig >> 3);
  const int bh = nid >> 5, b = bh >> 4;
  const int q0 = (nid & 31) * 64;
  const int t = threadIdx.x, l = t & 63, w = t >> 6;
  const int lc = l & 15, lg = l >> 4;

  // Q B-frags: col(q) = lc, k-elems(d) = h2*32 + lg*8 ..
  const unsigned short* qp = q + ((size_t)bh * 2048 + q0 + w * 16) * 64;
  bf16x8 qa[2];
  qa[0] = *(const bf16x8*)(qp + lc * 64 + lg * 8);
  qa[1] = *(const bf16x8*)(qp + lc * 64 + 32 + lg * 8);

  // ones B-frag (col 0 only) for row-sum accumulation on the MFMA pipe
  bf16x8 onesf;
#pragma unroll
  for (int j = 0; j < 8; ++j) ((unsigned short*)&onesf)[j] = (lc == 0) ? 0x3F80 : 0;

  const unsigned short* kp = k + (size_t)bh * 131072;
  const unsigned short* vp = vt + (size_t)bh * 131072;
  const unsigned char* mp = mb8 + (size_t)b * 4194304 + (size_t)(q0 + w * 16 + lc) * 2048;

  f32x4 oa[4] = {};
  f32x4 lsum = {};

  auto stage = [&](int buf, int kv0) {
    const int ldc = w * 64 + l;                   // 16B-chunk idx 0..255
    {
      const int row = ldc >> 3, ch = ldc & 7;     // K: [32 kv][64 d]
      const int sch = ch ^ SWZK(row);
      __builtin_amdgcn_global_load_lds(
          AS1(kp + (size_t)(kv0 + row) * 64 + sch * 8),
          AS3(&Kl[buf][(size_t)w * 512]), 16, 0, 0);
    }
    {
      const int row = ldc >> 2, ch = ldc & 3;     // V^T: [64 d][32 kv]
      const int sch = ch ^ SWZV(row);
      __builtin_amdgcn_global_load_lds(
          AS1(vp + (size_t)row * 2048 + kv0 + sch * 8),
          AS3(&Vl[buf][(size_t)w * 512]), 16, 0, 0);
    }
  };

  stage(0, 0);
  for (int tt = 0; tt < 64; ++tt) {
    const int kv0 = tt * 32;
    __syncthreads();                      // stage(tt) landed; prev reads done
    if (tt + 1 < 64) stage((tt + 1) & 1, kv0 + 32);
    const unsigned short* Kb = Kl[tt & 1];
    const unsigned short* Vb = Vl[tt & 1];

    // S^T accumulators initialized from mask bias (m==1 -> -2.4e5)
    f32x4 sa[2];
#pragma unroll
    for (int cb = 0; cb < 2; ++cb) {
      const unsigned mw = *(const unsigned*)(mp + kv0 + cb * 16 + lg * 4);
      sa[cb][0] = -240000.f * (float)(mw & 255u);
      sa[cb][1] = -240000.f * (float)((mw >> 8) & 255u);
      sa[cb][2] = -240000.f * (float)((mw >> 16) & 255u);
      sa[cb][3] = -240000.f * (float)(mw >> 24);
    }

    // S^T += K . Q^T
#pragma unroll
    for (int cb = 0; cb < 2; ++cb) {
      const int row = cb * 16 + lc;
#pragma unroll
      for (int h2 = 0; h2 < 2; ++h2) {
        bf16x8 kf = *(const bf16x8*)(Kb + row * 64 + ((h2 * 4 + lg) ^ SWZK(row)) * 8);
        sa[cb] = MFMA16(kf, qa[h2], sa[cb]);
      }
    }

    // P = exp2(S * 0.125*log2e) -> packed bf16 -> swizzled per-wave LDS
    unsigned short* Pw = (unsigned short*)Pl[w];
#pragma unroll
    for (int cb = 0; cb < 2; ++cb) {
      float2 ab, cd;
      ab.x = __builtin_amdgcn_exp2f(sa[cb][0] * 0.18033688f);
      ab.y = __builtin_amdgcn_exp2f(sa[cb][1] * 0.18033688f);
      cd.x = __builtin_amdgcn_exp2f(sa[cb][2] * 0.18033688f);
      cd.y = __builtin_amdgcn_exp2f(sa[cb][3] * 0.18033688f);
      __hip_bfloat162 lo = __float22bfloat162_rn(ab);
      __hip_bfloat162 hi = __float22bfloat162_rn(cd);
      uint2 pk;
      pk.x = *(unsigned*)&lo;
      pk.y = *(unsigned*)&hi;
      // chunk g = cb*2 + (lg>>1); slot = g ^ SWZV(q=lc); half = lg&1
      *(uint2*)(Pw + lc * 32 + ((cb * 2 + (lg >> 1)) ^ SWZV(lc)) * 8 + (lg & 1) * 4) = pk;
    }

    // O += P @ V ; lsum += P @ ones   (K=32, single k-step)
    bf16x8 pa = *(const bf16x8*)(Pw + lc * 32 + (lg ^ SWZV(lc)) * 8);
    lsum = MFMA16(pa, onesf, lsum);
#pragma unroll
    for (int db = 0; db < 4; ++db) {
      const int d = db * 16 + lc;
      bf16x8 vf = *(const bf16x8*)(Vb + d * 32 + (lg ^ SWZV(d)) * 8);
      oa[db] = MFMA16(pa, vf, oa[db]);
    }
  }

  // broadcast row sums (col 0 lives in lane lg*16) and write (B,S,D) bf16
  float li[4];
#pragma unroll
  for (int r = 0; r < 4; ++r) li[r] = __shfl(lsum[r], l & 48, 64);
#pragma unroll
  for (int r = 0; r < 4; ++r) {
    const float inv = 1.0f / li[r];
    const int row = q0 + w * 16 + lg * 4 + r;
    unsigned short* dst = ao + ((size_t)b * 2048 + row) * 1024 + (bh & 15) * 64;
#pragma unroll
    for (int db = 0; db < 4; ++db) dst[db * 16 + lc] = f2bf(oa[db][r] * inv);
  }
}

extern "C" void kernel_launch(void* const* d_in, const int* in_sizes, int n_in,
                              void* d_out, int out_size, void* d_ws, size_t ws_size,
                              hipStream_t stream) {
  const float* x = (const float*)d_in[0];
  const int* mask = (const int*)d_in[1];
  const float* Wq = (const float*)d_in[2];
  const float* Wk = (const float*)d_in[3];
  const float* Wv = (const float*)d_in[4];
  const float* Wo = (const float*)d_in[5];
  const float* bo = (const float*)d_in[6];

  unsigned short* ws = (unsigned short*)d_ws;
  unsigned short* xb = ws;                   // (B*S, D) bf16; reused as u8 mask later
  unsigned short* wqb = xb + 4194304;
  unsigned short* wkb = wqb + 1048576;
  unsigned short* wvb = wkb + 1048576;
  unsigned short* wob = wvb + 1048576;
  unsigned short* qb = wob + 1048576;        // (B,H,S,64) bf16
  unsigned short* kb = qb + 4194304;         // (B,H,S,64) bf16
  unsigned short* vtb = kb + 4194304;        // (B,H,64,S) bf16
  unsigned short* aob = vtb + 4194304;       // (B*S, D) bf16

  unsigned char* mb8 = (unsigned char*)xb;

  convert_all<<<dim3(15360), dim3(256), 0, stream>>>(x, Wq, Wk, Wv, Wo, ws);
  gemm_qkv<<<dim3(32, 8, 3), dim3(256), 0, stream>>>(xb, wqb, wkb, wvb, qb, kb, vtb);
  convert_mask<<<dim3(8192), dim3(256), 0, stream>>>(mask, mb8);
  attn_fwd<<<dim3(1024), dim3(256), 0, stream>>>(qb, kb, vtb, mb8, aob);
  gemm_out<<<dim3(64, 8), dim3(256), 0, stream>>>(aob, wob, bo, (float*)d_out);
}

// Round 7
// 228.823 us; speedup vs baseline: 1.2761x; 1.2761x over previous
//
#include <hip/hip_runtime.h>
#include <hip/hip_bf16.h>

typedef __attribute__((ext_vector_type(4))) float f32x4;
typedef __attribute__((ext_vector_type(16))) float f32x16;
typedef __attribute__((ext_vector_type(8))) short bf16x8;

#define MFMA16(a, b, c) __builtin_amdgcn_mfma_f32_16x16x32_bf16(a, b, c, 0, 0, 0)
#define MFMA32(a, b, c) __builtin_amdgcn_mfma_f32_32x32x16_bf16(a, b, c, 0, 0, 0)

#define AS1(p) ((const __attribute__((address_space(1))) void*)(p))
#define AS3(p) ((__attribute__((address_space(3))) void*)(p))

// XOR swizzle of 16B slot within a 128B row (8 slots)
#define SWZK(r) ((((r) & 7)) ^ ((((r) >> 3) & 1) << 2))

__device__ __forceinline__ unsigned short f2bf(float f) {
  union { float f; unsigned u; } x; x.f = f;
  unsigned r = x.u + 0x7fffu + ((x.u >> 16) & 1u);  // RNE
  return (unsigned short)(r >> 16);
}

// ------------- merged input conversion: f32->bf16 (+Wq pre-scale), mask->u8
// blocks [0,4096): 8.4M bf16 elems, 8/thread.  blocks [4096,12288): mask.
__global__ __launch_bounds__(256) void convert_inputs(
    const float* __restrict__ x, const float* __restrict__ wq,
    const float* __restrict__ wk, const float* __restrict__ wv,
    const float* __restrict__ wo, const int* __restrict__ mask,
    unsigned short* __restrict__ dst, unsigned char* __restrict__ mdst) {
  const int NX = 4194304, NW = 1048576;
  if (blockIdx.x < 4096) {
    const int i = blockIdx.x * 256 + threadIdx.x;
    const long base = (long)i * 8;
    const float* src; long off; float sc = 1.0f;
    if (base < NX) { src = x; off = base; }
    else {
      long j = base - NX; int wsI = (int)(j >> 20); off = j & (NW - 1);
      src = (wsI == 0) ? wq : (wsI == 1) ? wk : (wsI == 2) ? wv : wo;
      if (wsI == 0) sc = 0.18033688f;  // 0.125 * log2(e): QK lands in exp2 domain
    }
    float4 a = *(const float4*)(src + off);
    float4 b = *(const float4*)(src + off + 4);
    uint4 o;
    o.x = (unsigned)f2bf(a.x * sc) | ((unsigned)f2bf(a.y * sc) << 16);
    o.y = (unsigned)f2bf(a.z * sc) | ((unsigned)f2bf(a.w * sc) << 16);
    o.z = (unsigned)f2bf(b.x * sc) | ((unsigned)f2bf(b.y * sc) << 16);
    o.w = (unsigned)f2bf(b.z * sc) | ((unsigned)f2bf(b.w * sc) << 16);
    ((uint4*)dst)[i] = o;
  } else {
    const int i = (blockIdx.x - 4096) * 256 + threadIdx.x;  // x4 elements
    const int4 v = ((const int4*)mask)[i];
    uchar4 r;
    r.x = (unsigned char)v.x; r.y = (unsigned char)v.y;
    r.z = (unsigned char)v.z; r.w = (unsigned char)v.w;
    ((uchar4*)mdst)[i] = r;
  }
}

// ---------------- templated BMxBN NT GEMM mainloop (C = A * W^T), K=1024 ---
template <int BM, int BN>
__device__ __forceinline__ void gemm_nt(
    const unsigned short* __restrict__ A, const unsigned short* __restrict__ Bw,
    int m0, int n0, unsigned short* Al, unsigned short* Bl, f32x4* acc) {
  const int t = threadIdx.x;
  const int l = t & 63;
  const int w = t >> 6, wr = w >> 1, wc = w & 1;
  const int lc = l & 15, lg = l >> 4;
  constexpr int MI = BM / 32, NJ = BN / 32;
  constexpr int ASZ = BM * 32, BSZ = BN * 32;

  auto stage = [&](int buf, int kt) {
    const int k0 = kt * 32;
#pragma unroll
    for (int c = 0; c < BM / 64; ++c) {
      const int e = (t + c * 256) * 8;
      __builtin_amdgcn_global_load_lds(
          AS1(A + (size_t)(m0 + (e >> 5)) * 1024 + k0 + (e & 31)),
          AS3(Al + buf * ASZ + e), 16, 0, 0);
    }
#pragma unroll
    for (int c = 0; c < BN / 64; ++c) {
      const int e = (t + c * 256) * 8;
      __builtin_amdgcn_global_load_lds(
          AS1(Bw + (size_t)(n0 + (e >> 5)) * 1024 + k0 + (e & 31)),
          AS3(Bl + buf * BSZ + e), 16, 0, 0);
    }
  };

  stage(0, 0);
#pragma unroll 2
  for (int kt = 0; kt < 32; ++kt) {
    __syncthreads();
    if (kt + 1 < 32) stage((kt + 1) & 1, kt + 1);
    const unsigned short* Ab = Al + (kt & 1) * ASZ;
    const unsigned short* Bb = Bl + (kt & 1) * BSZ;
    bf16x8 af[MI], bfr[NJ];
#pragma unroll
    for (int i = 0; i < MI; ++i)
      af[i] = *(const bf16x8*)(Ab + (wr * (BM / 2) + i * 16 + lc) * 32 + lg * 8);
#pragma unroll
    for (int j = 0; j < NJ; ++j)
      bfr[j] = *(const bf16x8*)(Bb + (wc * (BN / 2) + j * 16 + lc) * 32 + lg * 8);
#pragma unroll
    for (int i = 0; i < MI; ++i)
#pragma unroll
      for (int j = 0; j < NJ; ++j)
        acc[i * NJ + j] = MFMA16(af[i], bfr[j], acc[i * NJ + j]);
  }
}

// ---------------- QKV projection: Q,K -> (B,H,S,64); V -> (B,H,64,S) -------
__global__ __launch_bounds__(256) void gemm_qkv(
    const unsigned short* __restrict__ xb,
    const unsigned short* __restrict__ wqb, const unsigned short* __restrict__ wkb,
    const unsigned short* __restrict__ wvb,
    unsigned short* __restrict__ q, unsigned short* __restrict__ k,
    unsigned short* __restrict__ vt) {
  __shared__ unsigned short Al[2 * 4096], Bl[2 * 4096];
  const int z = blockIdx.z;
  const unsigned short* Bw = (z == 0) ? wqb : (z == 1) ? wkb : wvb;
  const int m0 = blockIdx.x * 128, n0 = blockIdx.y * 128;
  f32x4 acc[16] = {};
  gemm_nt<128, 128>(xb, Bw, m0, n0, Al, Bl, acc);

  const int l = threadIdx.x & 63, w = threadIdx.x >> 6;
  const int wr = w >> 1, wc = w & 1, lc = l & 15, lg = l >> 4;

  if (z == 2) {
#pragma unroll
    for (int i = 0; i < 4; ++i)
#pragma unroll
      for (int j = 0; j < 4; ++j) {
        const int m = m0 + wr * 64 + i * 16 + lg * 4;
        const int n = n0 + wc * 64 + j * 16 + lc;
        const int b = m >> 11, s = m & 2047, hh = n >> 6, hd = n & 63;
        ushort4 pk;
        pk.x = f2bf(acc[i * 4 + j][0]); pk.y = f2bf(acc[i * 4 + j][1]);
        pk.z = f2bf(acc[i * 4 + j][2]); pk.w = f2bf(acc[i * 4 + j][3]);
        *(ushort4*)(vt + (size_t)((b << 4) + hh) * 131072 + (size_t)hd * 2048 + s) = pk;
      }
  } else {
    unsigned short* C = (z == 0) ? q : k;
#pragma unroll
    for (int i = 0; i < 4; ++i)
#pragma unroll
      for (int j = 0; j < 4; ++j)
#pragma unroll
        for (int r = 0; r < 4; ++r) {
          const int m = m0 + wr * 64 + i * 16 + lg * 4 + r;
          const int n = n0 + wc * 64 + j * 16 + lc;
          const int b = m >> 11, s = m & 2047, hh = n >> 6, hd = n & 63;
          C[(size_t)((b << 4) + hh) * 131072 + s * 64 + hd] = f2bf(acc[i * 4 + j][r]);
        }
  }
}

// ---------------- output projection: out = ao @ Wo^T + bo, 64x128 tiles ----
__global__ __launch_bounds__(256) void gemm_out(
    const unsigned short* __restrict__ ao, const unsigned short* __restrict__ wob,
    const float* __restrict__ bias, float* __restrict__ out) {
  __shared__ unsigned short Al[2 * 2048], Bl[2 * 4096];
  const int m0 = blockIdx.x * 64, n0 = blockIdx.y * 128;
  f32x4 acc[8] = {};
  gemm_nt<64, 128>(ao, wob, m0, n0, Al, Bl, acc);

  const int l = threadIdx.x & 63, w = threadIdx.x >> 6;
  const int wr = w >> 1, wc = w & 1, lc = l & 15, lg = l >> 4;
#pragma unroll
  for (int i = 0; i < 2; ++i)
#pragma unroll
    for (int j = 0; j < 4; ++j)
#pragma unroll
      for (int r = 0; r < 4; ++r) {
        const int m = m0 + wr * 32 + i * 16 + lg * 4 + r;
        const int n = n0 + wc * 64 + j * 16 + lc;
        out[(size_t)m * 1024 + n] = acc[i * 4 + j][r] + bias[n];
      }
}

// ---------------- flash attention: 32x32 MFMA, in-register softmax ---------
// S^T = K.Q^T (mfma32): lane holds q = lane&31 for all kv (16 regs x 2 cb).
// P -> A-frag via cvt_pk_bf16 + permlane32_swap (no P LDS). Mask staged u8.
// Q-tile 128 (4 waves x 32q), KVB = 64, grid 512 = 2 blocks/CU.
__global__ __launch_bounds__(256, 2) void attn_fwd(
    const unsigned short* __restrict__ q, const unsigned short* __restrict__ k,
    const unsigned short* __restrict__ vt, const unsigned char* __restrict__ mb8,
    unsigned short* __restrict__ ao) {
  __shared__ unsigned short Kl[2][4096];  // [64 kv][64 d] swizzled, 8KB x2
  __shared__ unsigned short Vl[2][4096];  // [64 d][64 kv] swizzled, 8KB x2
  __shared__ unsigned char Ml[2][8192];   // [128 q][64 kv] u8, dword-swizzled
  __shared__ float Ll[128];
  // XCD-aware bijective swizzle: 512 blocks, 8 XCDs, 64 consecutive per XCD
  const int orig = blockIdx.x;
  const int nid = (orig & 7) * 64 + (orig >> 3);
  const int bh = nid >> 4, b = bh >> 4, h = bh & 15;
  const int q0 = (nid & 15) * 128;
  const int t = threadIdx.x, l = t & 63, w = t >> 6;
  const int lq = l & 31, hh = l >> 5;
  const int qq = w * 32 + lq;  // q row within block tile

  // Q B-frags (col=q=lane&31, k=d=s*16+hh*8+j), held all kernel
  const unsigned short* qp = q + ((size_t)bh * 2048 + q0 + qq) * 64;
  bf16x8 qa[4];
#pragma unroll
  for (int s = 0; s < 4; ++s) qa[s] = *(const bf16x8*)(qp + s * 16 + hh * 8);

  const unsigned short* kp = k + (size_t)bh * 131072;
  const unsigned short* vp = vt + (size_t)bh * 131072;
  const unsigned char* mp = mb8 + (size_t)b * 4194304;

  f32x16 oa[2] = {};
  float lsum = 0.f;

  auto stage = [&](int buf, int kv0) {
#pragma unroll
    for (int c = 0; c < 2; ++c) {
      const int idx = c * 256 + w * 64 + l;  // 16B-chunk 0..511
      {
        const int row = idx >> 3, ch = idx & 7;  // K: [64 kv][8 chunks]
        __builtin_amdgcn_global_load_lds(
            AS1(kp + (size_t)(kv0 + row) * 64 + (ch ^ SWZK(row)) * 8),
            AS3(&Kl[buf][(c * 256 + w * 64) * 8]), 16, 0, 0);
      }
      {
        const int row = idx >> 3, ch = idx & 7;  // V^T: [64 d][8 chunks]
        __builtin_amdgcn_global_load_lds(
            AS1(vp + (size_t)row * 2048 + kv0 + (ch ^ SWZK(row)) * 8),
            AS3(&Vl[buf][(c * 256 + w * 64) * 8]), 16, 0, 0);
      }
      {
        const int row = idx >> 2, ch = idx & 3;  // M: [128 q][4 chunks]
        __builtin_amdgcn_global_load_lds(
            AS1(mp + (size_t)(q0 + row) * 2048 + kv0 + (ch ^ ((row >> 1) & 3)) * 16),
            AS3(&Ml[buf][(c * 256 + w * 64) * 16]), 16, 0, 0);
      }
    }
  };

  stage(0, 0);
  for (int tt = 0; tt < 32; ++tt) {
    const int kv0 = tt * 64;
    __syncthreads();  // stage(tt) landed; prev-tile reads done
    if (tt + 1 < 32) stage((tt + 1) & 1, kv0 + 64);
    const unsigned short* Kb = Kl[tt & 1];
    const unsigned short* Vb = Vl[tt & 1];
    const unsigned char* Mb = Ml[tt & 1];

    // S^T += K . Q^T  (A=K rows kv, B=Q cols q; QK pre-scaled to exp2 domain)
    f32x16 sa[2] = {};
#pragma unroll
    for (int s = 0; s < 4; ++s) {
#pragma unroll
      for (int cb = 0; cb < 2; ++cb) {
        const int row = cb * 32 + lq;
        bf16x8 kf = *(const bf16x8*)(Kb + row * 64 + (((2 * s + hh) ^ SWZK(row))) * 8);
        sa[cb] = MFMA32(kf, qa[s], sa[cb]);
      }
    }

    // mask (u8 dword from LDS) + exp2, in place; accumulate row sum
#pragma unroll
    for (int cb = 0; cb < 2; ++cb)
#pragma unroll
      for (int g = 0; g < 4; ++g) {
        const int sdw = 8 * cb + 2 * g + hh;
        const int sl = sdw ^ (((qq >> 1) & 3) << 2);
        const unsigned mdw = *(const unsigned*)(Mb + qq * 64 + sl * 4);
#pragma unroll
        for (int i = 0; i < 4; ++i) {
          const float mf = (float)((mdw >> (8 * i)) & 255u);
          const float e = __builtin_amdgcn_exp2f(fmaf(mf, -100.f, sa[cb][4 * g + i]));
          sa[cb][4 * g + i] = e;
          lsum += e;
        }
      }

    // P -> A-frags in-register (cvt_pk + permlane32_swap), then O += P @ V
#pragma unroll
    for (int s = 0; s < 4; ++s) {
      const int cb = s >> 1, gb = 2 * (s & 1);
      unsigned pk00, pk01, pk10, pk11;
      asm("v_cvt_pk_bf16_f32 %0, %1, %2" : "=v"(pk00) : "v"(sa[cb][4 * gb + 0]), "v"(sa[cb][4 * gb + 1]));
      asm("v_cvt_pk_bf16_f32 %0, %1, %2" : "=v"(pk01) : "v"(sa[cb][4 * gb + 2]), "v"(sa[cb][4 * gb + 3]));
      asm("v_cvt_pk_bf16_f32 %0, %1, %2" : "=v"(pk10) : "v"(sa[cb][4 * gb + 4]), "v"(sa[cb][4 * gb + 5]));
      asm("v_cvt_pk_bf16_f32 %0, %1, %2" : "=v"(pk11) : "v"(sa[cb][4 * gb + 6]), "v"(sa[cb][4 * gb + 7]));
      asm("v_permlane32_swap_b32 %0, %1" : "+v"(pk00), "+v"(pk10));  // -> d0, d2
      asm("v_permlane32_swap_b32 %0, %1" : "+v"(pk01), "+v"(pk11));  // -> d1, d3
      union { int4 i; bf16x8 v; } fr;
      fr.i = make_int4(pk00, pk01, pk10, pk11);
#pragma unroll
      for (int db = 0; db < 2; ++db) {
        const int row = db * 32 + lq;
        bf16x8 vf = *(const bf16x8*)(Vb + row * 64 + (((2 * s + hh) ^ SWZK(row))) * 8);
        oa[db] = MFMA32(fr.v, vf, oa[db]);
      }
    }
  }

  // combine row sums across lane halves, broadcast reciprocals via LDS
  lsum += __shfl_xor(lsum, 32, 64);
  Ll[qq] = __builtin_amdgcn_rcpf(lsum);
  __syncthreads();

#pragma unroll
  for (int r = 0; r < 16; ++r) {
    const int row = (r & 3) + 8 * (r >> 2) + 4 * hh;
    const float inv = Ll[w * 32 + row];
    unsigned short* dst = ao + ((size_t)b * 2048 + q0 + w * 32 + row) * 1024 + h * 64;
    dst[lq] = f2bf(oa[0][r] * inv);
    dst[32 + lq] = f2bf(oa[1][r] * inv);
  }
}

extern "C" void kernel_launch(void* const* d_in, const int* in_sizes, int n_in,
                              void* d_out, int out_size, void* d_ws, size_t ws_size,
                              hipStream_t stream) {
  const float* x = (const float*)d_in[0];
  const int* mask = (const int*)d_in[1];
  const float* Wq = (const float*)d_in[2];
  const float* Wk = (const float*)d_in[3];
  const float* Wv = (const float*)d_in[4];
  const float* Wo = (const float*)d_in[5];
  const float* bo = (const float*)d_in[6];

  unsigned short* ws = (unsigned short*)d_ws;
  unsigned short* xb = ws;                   // (B*S, D) bf16
  unsigned short* wqb = xb + 4194304;        // pre-scaled by 0.125*log2(e)
  unsigned short* wkb = wqb + 1048576;
  unsigned short* wvb = wkb + 1048576;
  unsigned short* wob = wvb + 1048576;
  unsigned short* qb = wob + 1048576;        // (B,H,S,64) bf16
  unsigned short* kb = qb + 4194304;         // (B,H,S,64) bf16
  unsigned short* vtb = kb + 4194304;        // (B,H,64,S) bf16
  unsigned short* aob = vtb + 4194304;       // (B*S, D) bf16
  unsigned char* mb8 = (unsigned char*)(aob + 4194304);  // 8.4MB u8 mask

  convert_inputs<<<dim3(12288), dim3(256), 0, stream>>>(x, Wq, Wk, Wv, Wo, mask, ws, mb8);
  gemm_qkv<<<dim3(32, 8, 3), dim3(256), 0, stream>>>(xb, wqb, wkb, wvb, qb, kb, vtb);
  attn_fwd<<<dim3(512), dim3(256), 0, stream>>>(qb, kb, vtb, mb8, aob);
  gemm_out<<<dim3(64, 8), dim3(256), 0, stream>>>(aob, wob, bo, (float*)d_out);
}